// Round 14
// baseline (834.343 us; speedup 1.0000x reference)
//
#include <hip/hip_runtime.h>

typedef _Float16 f16;
typedef _Float16 f16x8 __attribute__((ext_vector_type(8)));
typedef _Float16 f16x4 __attribute__((ext_vector_type(4)));
typedef float    f32x4 __attribute__((ext_vector_type(4)));
typedef float    f32x16 __attribute__((ext_vector_type(16)));

#define MFMA16(a,b,c) __builtin_amdgcn_mfma_f32_16x16x32_f16(a,b,c,0,0,0)
#define MFMA32(a,b,c) __builtin_amdgcn_mfma_f32_32x32x16_f16(a,b,c,0,0,0)

#define AS1 __attribute__((address_space(1)))
#define AS3 __attribute__((address_space(3)))
#define WAITVM(N) asm volatile("s_waitcnt vmcnt(" #N ")" ::: "memory")

#define NPIX 65536
// activation layout (halves): [row 258][cb 7][h 2][k16 2][kh 2][px 258][8]
#define PXS   8
#define KHS   2064      // 258*8
#define K16S  4128
#define HS    8256
#define CBS   16512
#define ROWH  115584    // halves per row
#define RBYTES 231168
#define SBUF  ((size_t)258*RBYTES)   // 59,641,344 B

// conv weight pack (halves): 117 LIVE slices per layer, slice = [sel 2][ob 7][lane 64][8]
#define PKSUB  7168
#define PK_CONV 903168
#define NMICRO 117

// last (1x1) pack strides (halves)
#define PKL_CB  5120
#define PKL_BI  35840

#define ASTG 14336
#define BSTG 17408      // main [8 pl][128 slot]*16B = 16384 + halo 1024

// ---------------- weight packing: 3x3 convs, 32x32 A-fragment order ----------------
__global__ void k_pack_conv(const float* __restrict__ head_w,
                            const float* __restrict__ conv_w,
                            f16* __restrict__ dst)
{
    int t = blockIdx.x*256 + threadIdx.x;
    int lane = t & 63; t >>= 6;
    int ob  = t % 7;  t /= 7;
    int sel = t & 1;  t >>= 1;
    int kx  = t % 3;  t /= 3;
    int k16 = t & 1;  t >>= 1;
    int cb  = t % 7;  t /= 7;
    int ky  = t % 3;  t /= 3;
    int li  = t;
    if (li >= 4) return;
    if (cb == 6 && k16 == 1) return;          // dead slice: ic 208..223 all zero
    const float* W = (li == 0) ? head_w : (conv_w + (size_t)(li-1)*196*196*9);
    int oc  = ob*32 + (lane & 31);
    int ic0 = cb*32 + k16*16 + (lane >> 5)*8;
    int tap = ky*3 + kx;
    f16x8 v;
#pragma unroll
    for (int j = 0; j < 8; ++j) {
        int ic = ic0 + j;
        float x = 0.f;
        if (oc < 196 && ic < 196) x = W[((size_t)oc*196 + ic)*9 + tap];
        f16 h = (f16)x;
        v[j] = (sel == 0) ? h : (f16)(x - (float)h);
    }
    int pos = ky*39 + ((cb < 6) ? (cb*6 + k16*3 + kx) : (36 + kx));
    *(f16x8*)(dst + (size_t)li*PK_CONV + (size_t)pos*PKSUB
              + (size_t)(sel*7 + ob)*512 + (size_t)lane*8) = v;
}

__global__ void k_pack_last(const float* __restrict__ last_w, f16* __restrict__ dst)
{
    int t = blockIdx.x*256 + threadIdx.x;
    if (t >= 4*7*5*2*64) return;
    int lane = t & 63; t >>= 6;
    int sel  = t & 1;  t >>= 1;
    int ob   = t % 5;  t /= 5;
    int cb   = t % 7;  t /= 7;
    int bi   = t;
    int oc = ob*16 + (lane & 15);
    int k0 = cb*32 + (lane >> 4)*8;
    f16x8 v;
#pragma unroll
    for (int j = 0; j < 8; ++j) {
        int k = k0 + j;
        float x = 0.f;
        if (oc < 68 && k < 196) x = last_w[(size_t)oc*784 + bi*196 + k];
        f16 h = (f16)x;
        v[j] = (sel == 0) ? h : (f16)(x - (float)h);
    }
    *(f16x8*)(dst + (((size_t)((bi*7+cb)*5 + ob)*2 + sel)*64 + lane)*8) = v;
}

// ---------------- zero the halo px-slots (0 and 257) of every row/slice ----------------
__global__ void k_zero_halo(f16* __restrict__ bufA, f16* __restrict__ bufB)
{
    int c = blockIdx.x*256 + threadIdx.x;
    int end = c & 1; c >>= 1;
    int kh  = c & 1; c >>= 1;
    int k16 = c & 1; c >>= 1;
    int h   = c & 1; c >>= 1;
    int cb  = c % 7; c /= 7;
    int row = c % 258; c /= 258;
    if (c >= 2) return;
    f16* base = (c == 0) ? bufA : bufB;
    f16* p = base + (size_t)row*ROWH + cb*CBS + h*HS + k16*K16S + kh*KHS + (end ? 257 : 0)*PXS;
    f16x8 z = {(f16)0,(f16)0,(f16)0,(f16)0,(f16)0,(f16)0,(f16)0,(f16)0};
    *(f16x8*)p = z;
}

// ---------------- warp + concat → x0 ----------------
struct Gath { int o00,o01,o10,o11; float w00,w01,w10,w11; };

__device__ inline Gath mk_gath(float pxf, float pyf)
{
    float x0 = floorf(pxf), y0 = floorf(pyf);
    float x1 = x0 + 1.f, y1 = y0 + 1.f;
    float wx1 = pxf - x0, wx0 = 1.f - wx1;
    float wy1 = pyf - y0, wy0 = 1.f - wy1;
    bool vx0 = (x0 >= 0.f) && (x0 <= 255.f);
    bool vx1 = (x1 >= 0.f) && (x1 <= 255.f);
    bool vy0 = (y0 >= 0.f) && (y0 <= 255.f);
    bool vy1 = (y1 >= 0.f) && (y1 <= 255.f);
    int ix0 = min(max((int)x0, 0), 255);
    int ix1 = min(max((int)x1, 0), 255);
    int iy0 = min(max((int)y0, 0), 255);
    int iy1 = min(max((int)y1, 0), 255);
    Gath g;
    g.o00 = iy0*256 + ix0; g.w00 = (vx0 && vy0) ? wx0*wy0 : 0.f;
    g.o01 = iy0*256 + ix1; g.w01 = (vx1 && vy0) ? wx1*wy0 : 0.f;
    g.o10 = iy1*256 + ix0; g.w10 = (vx0 && vy1) ? wx0*wy1 : 0.f;
    g.o11 = iy1*256 + ix1; g.w11 = (vx1 && vy1) ? wx1*wy1 : 0.f;
    return g;
}

__device__ inline void store4n(f16* __restrict__ rowb, int slot, int c0,
                               float a, float b, float c, float d)
{
    f16x4 hi, lo;
    f16 h;
    h = (f16)a; hi[0] = h; lo[0] = (f16)(a - (float)h);
    h = (f16)b; hi[1] = h; lo[1] = (f16)(b - (float)h);
    h = (f16)c; hi[2] = h; lo[2] = (f16)(c - (float)h);
    h = (f16)d; hi[3] = h; lo[3] = (f16)(d - (float)h);
    int cb = c0 >> 5, w32 = c0 & 31;
    f16* p = rowb + cb*CBS + (w32 >> 4)*K16S + ((w32 >> 3) & 1)*KHS
                 + (size_t)slot*PXS + (w32 & 7);
    *(f16x4*)p        = hi;
    *(f16x4*)(p + HS) = lo;
}

__global__ void k_warp_concat(const float* __restrict__ f0, const float* __restrict__ f1,
                              const float* __restrict__ fd, const float* __restrict__ flow,
                              f16* __restrict__ out)
{
    int px = blockIdx.x*256 + threadIdx.x;
    int row = px >> 8, col = px & 255;
    f16* rowb = out + (size_t)(row+1)*ROWH;
    int slot = col + 1;
    Gath g0 = mk_gath((float)col + flow[px],          (float)row + flow[NPIX   + px]);
    Gath g1 = mk_gath((float)col + flow[2*NPIX + px], (float)row + flow[3*NPIX + px]);
#pragma unroll
    for (int c = 0; c < 64; c += 4) {
        float v[4];
#pragma unroll
        for (int r = 0; r < 4; ++r) {
            const float* im = f0 + (size_t)(c+r)*NPIX;
            v[r] = g0.w00*im[g0.o00] + g0.w01*im[g0.o01] + g0.w10*im[g0.o10] + g0.w11*im[g0.o11];
        }
        store4n(rowb, slot, c, v[0], v[1], v[2], v[3]);
    }
#pragma unroll
    for (int c = 0; c < 64; c += 4) {
        float v[4];
#pragma unroll
        for (int r = 0; r < 4; ++r) {
            const float* im = f1 + (size_t)(c+r)*NPIX;
            v[r] = g1.w00*im[g1.o00] + g1.w01*im[g1.o01] + g1.w10*im[g1.o10] + g1.w11*im[g1.o11];
        }
        store4n(rowb, slot, 64 + c, v[0], v[1], v[2], v[3]);
    }
#pragma unroll
    for (int c = 0; c < 64; c += 4) {
        store4n(rowb, slot, 128 + c, fd[(size_t)(c+0)*NPIX + px], fd[(size_t)(c+1)*NPIX + px],
                                     fd[(size_t)(c+2)*NPIX + px], fd[(size_t)(c+3)*NPIX + px]);
    }
    store4n(rowb, slot, 192, flow[px], flow[NPIX+px], flow[2*NPIX+px], flow[3*NPIX+px]);
#pragma unroll
    for (int c = 196; c < 224; c += 4) store4n(rowb, slot, c, 0.f, 0.f, 0.f, 0.f);
}

// ---------------- 3x3 conv: self-synced waves, idempotent duplicate staging --------
// 512 blocks x 256 thr (4 waves). Block tile = 224 oc x 128 px. 117 live micros.
// Each wave stages exactly what it reads (A: its ocg frag set; B: its pxg half);
// pair partners duplicate the same bytes (benign). Sync = per-wave counted vmcnt
// + rendezvous-only s_barrier every 2nd micro (A tri-buffer, B dbuf — drift<2 safe).
template<int NOB, int OB0>
__device__ __forceinline__ void conv_body(
    const f16* __restrict__ in, f16* __restrict__ out,
    const f16* __restrict__ pack, const float* __restrict__ alpha,
    const float* __restrict__ mask,
    char* Asb, char* Bsb, int row, int cb0, int lane, int pxg, int bid)
{
    int l31 = lane & 31, lk = lane >> 5;

    f32x16 acc[NOB][2];
#pragma unroll
    for (int o = 0; o < NOB; ++o)
#pragma unroll
        for (int pt = 0; pt < 2; ++pt)
#pragma unroll
            for (int e = 0; e < 16; ++e) acc[o][pt][e] = 0.f;

    // stage this wave's A frag set for micro qi into A-buffer b: 2*NOB DMA
    auto stageA = [&](int b, int qi) {
        const f16* src = pack + (size_t)qi*PKSUB;
        char* dst = Asb + b*ASTG;
#pragma unroll
        for (int j = 0; j < NOB; ++j) {
            int fr1 = OB0 + j, fr2 = 7 + OB0 + j;
            __builtin_amdgcn_global_load_lds(
                (const AS1 void*)(src + fr1*512 + lane*8),
                (AS3 void*)(dst + fr1*1024 + lane*16), 16, 0, 0);
            __builtin_amdgcn_global_load_lds(
                (const AS1 void*)(src + fr2*512 + lane*8),
                (AS3 void*)(dst + fr2*1024 + lane*16), 16, 0, 0);
        }
    };

    // stage this wave's B half (pxg): 8 main DMA + 1 halo DMA = 9
    auto stageB = [&](int b, const f16* g) {
        char* dst = Bsb + b*BSTG;
#pragma unroll
        for (int u = 0; u < 8; ++u) {
            __builtin_amdgcn_global_load_lds(
                (const AS1 void*)(g + (size_t)u*KHS + (size_t)(cb0 + pxg*64 + lane)*PXS),
                (AS3 void*)(dst + (u*128 + pxg*64)*16 + lane*16), 16, 0, 0);
        }
        int idx = lane & 15;
        int pl  = idx >> 1;
        int il  = idx & 1;
        __builtin_amdgcn_global_load_lds(
            (const AS1 void*)(g + (size_t)pl*KHS + (size_t)(cb0 + 128 + il)*PXS),
            (AS3 void*)(dst + 16384 + lane*16), 16, 0, 0);
    };

    // B read address: main [pl][128 slots] or halo (slots 128,129)
    auto bptr = [&](const char* Bb, int pl, int sl) -> const char* {
        return (sl < 128) ? (Bb + pl*2048 + sl*16)
                          : (Bb + 16384 + pl*32 + (sl - 128)*16);
    };

    const f16* g = in + (size_t)row*ROWH;     // (ky=0, cb=0)
    stageB(0, g);
    stageA(0, 0);

    int acur = 0, bsel = 0, q = 0;
    for (int ky = 0; ky < 3; ++ky) {
        for (int cb = 0; cb < 7; ++cb) {
            bool lastPhase = (ky == 2) && (cb == 6);
            int nk16 = (cb == 6) ? 1 : 2;
            const f16* gn = (cb < 6) ? (g + CBS) : (g + ROWH - 6*CBS);
            for (int k16 = 0; k16 < 2; ++k16) {
                if (k16 >= nk16) break;
#pragma unroll
                for (int kx = 0; kx < 3; ++kx) {
                    int anx = (acur == 2) ? 0 : (acur + 1);
                    bool aload = (q + 1 < NMICRO);
                    if (aload) stageA(anx, q + 1);
                    // per-wave counted wait: retire A(q) (+ B when it's 2 micros old)
                    if (aload) {
                        if (k16 == 0 && kx == 1 && !lastPhase) {
                            if (NOB == 4) WAITVM(17); else WAITVM(15);
                        } else {
                            if (NOB == 4) WAITVM(8);  else WAITVM(6);
                        }
                    } else {
                        WAITVM(0);
                    }
                    if ((q & 1) == 0) __builtin_amdgcn_s_barrier();
                    if (k16 == 0 && kx == 0 && !lastPhase) stageB(bsel ^ 1, gn);

                    const char* ab = Asb + acur*ASTG;
                    const char* Bb = Bsb + bsel*BSTG;
                    f16x8 Bh[2], Bl[2];
#pragma unroll
                    for (int pt = 0; pt < 2; ++pt) {
                        int sl = pxg*64 + l31 + kx + pt*32;
                        int plh = k16*2 + lk;
                        Bh[pt] = *(const f16x8*)bptr(Bb, plh, sl);
                        Bl[pt] = *(const f16x8*)bptr(Bb, 4 + plh, sl);
                    }
                    __builtin_amdgcn_s_setprio(1);
#pragma unroll
                    for (int o = 0; o < NOB; ++o) {
                        f16x8 Ah = *(const f16x8*)(ab + (OB0 + o)*1024 + lane*16);
                        f16x8 Al = *(const f16x8*)(ab + (7 + OB0 + o)*1024 + lane*16);
#pragma unroll
                        for (int pt = 0; pt < 2; ++pt) {
                            acc[o][pt] = MFMA32(Ah, Bh[pt], acc[o][pt]);
                            acc[o][pt] = MFMA32(Al, Bh[pt], acc[o][pt]);
                            acc[o][pt] = MFMA32(Ah, Bl[pt], acc[o][pt]);
                        }
                    }
                    __builtin_amdgcn_s_setprio(0);
                    acur = anx;
                    ++q;
                }
            }
            if (!lastPhase) { g = gn; bsel ^= 1; }
        }
    }

    // epilogue: prelu * mask, split-f16 store into the channel-major layout
    int colbase = cb0 + pxg*64;
    float mv[2];
#pragma unroll
    for (int pt = 0; pt < 2; ++pt) mv[pt] = mask[row*256 + colbase + pt*32 + l31];
#pragma unroll
    for (int o = 0; o < NOB; ++o) {
        int ob = OB0 + o;
#pragma unroll
        for (int qg = 0; qg < 4; ++qg) {
            int oc0 = ob*32 + 8*qg + 4*lk;
            f32x4 a4 = *(const f32x4*)(alpha + min(oc0, 192));
#pragma unroll
            for (int pt = 0; pt < 2; ++pt) {
                f16x4 hi, lo;
#pragma unroll
                for (int e = 0; e < 4; ++e) {
                    float v = acc[o][pt][qg*4 + e];
                    v = (v >= 0.f ? v : a4[e]*v) * mv[pt];
                    f16 h = (f16)v;
                    hi[e] = h;
                    lo[e] = (f16)(v - (float)h);
                }
                f16* p = out + (size_t)(row+1)*ROWH + (size_t)(colbase + pt*32 + l31 + 1)*PXS
                       + lk*4 + ob*CBS + (qg >> 1)*K16S + (qg & 1)*KHS;
                *(f16x4*)p        = hi;
                *(f16x4*)(p + HS) = lo;
            }
        }
    }
}

__global__ __launch_bounds__(256, 2)
void k_conv32(const f16* __restrict__ in, f16* __restrict__ out,
              const f16* __restrict__ pack, const float* __restrict__ alpha,
              const float* __restrict__ mask)
{
    __shared__ __align__(16) char As[3][ASTG];
    __shared__ __align__(16) char Bs[2][BSTG];

    int bid = blockIdx.x;
    int wg  = (bid & 7)*64 + (bid >> 3);      // bijective XCD swizzle (512 % 8 == 0)
    int row  = wg >> 1;
    int half = wg & 1;
    int tid  = threadIdx.x;
    int lane = tid & 63;
    int w    = tid >> 6;
    int ocg  = ((w >> 1) ^ bid) & 1;          // parity: each SIMD gets one 4-ob + one 3-ob wave
    int pxg  = w & 1;
    int cb0 = half*128;

    if (ocg == 0)
        conv_body<4,0>(in, out, pack, alpha, mask, &As[0][0], &Bs[0][0], row, cb0, lane, pxg, bid);
    else
        conv_body<3,4>(in, out, pack, alpha, mask, &As[0][0], &Bs[0][0], row, cb0, lane, pxg, bid);
}

// ---------------- incremental 1x1 last-conv: acc[px][72] (+= / init with bias) ----------------
__global__ __launch_bounds__(256, 4)
void k_acc_last(const f16* __restrict__ in, const f16* __restrict__ pack,
                const float* __restrict__ bias, float* __restrict__ accp, int bi)
{
    int lane = threadIdx.x & 63;
    int wid  = (blockIdx.x << 2) | (threadIdx.x >> 6);
    int row  = wid >> 3;
    int col0 = (wid & 7) << 5;
    int l15 = lane & 15, lk = lane >> 4;

    f32x4 acc[5][2];
#pragma unroll
    for (int i = 0; i < 5; ++i)
#pragma unroll
        for (int j = 0; j < 2; ++j)
            acc[i][j] = (f32x4){0.f, 0.f, 0.f, 0.f};

    const f16* bb = in + (size_t)(row+1)*ROWH + (size_t)(col0 + l15 + 1)*PXS
                  + (lk >> 1)*K16S + (lk & 1)*KHS;
    const f16* ap = pack + (size_t)bi*PKL_BI + (size_t)lane*8;
    for (int cb = 0; cb < 7; ++cb) {
        f16x8 bh[2], bl[2];
#pragma unroll
        for (int pb = 0; pb < 2; ++pb) {
            const f16* p = bb + cb*CBS + pb*16*PXS;
            bh[pb] = *(const f16x8*)p;
            bl[pb] = *(const f16x8*)(p + HS);
        }
        const f16* a = ap + cb*PKL_CB;
#pragma unroll
        for (int ob = 0; ob < 5; ++ob) {
            f16x8 ah = *(const f16x8*)(a + ob*1024);
            f16x8 al = *(const f16x8*)(a + ob*1024 + 512);
#pragma unroll
            for (int pb = 0; pb < 2; ++pb) {
                acc[ob][pb] = MFMA16(ah, bh[pb], acc[ob][pb]);
                acc[ob][pb] = MFMA16(ah, bl[pb], acc[ob][pb]);
                acc[ob][pb] = MFMA16(al, bh[pb], acc[ob][pb]);
            }
        }
    }
#pragma unroll
    for (int ob = 0; ob < 5; ++ob) {
        int oc0 = ob*16 + lk*4;
        if (oc0 >= 72) continue;           // accp stride is 72 floats
#pragma unroll
        for (int pb = 0; pb < 2; ++pb) {
            int px = row*256 + col0 + pb*16 + l15;
            float* dst = accp + (size_t)px*72 + oc0;
            f32x4 d = acc[ob][pb];
            if (bi == 0) {
                f32x4 b4;
#pragma unroll
                for (int r = 0; r < 4; ++r) b4[r] = bias[min(oc0 + r, 67)];
                *(f32x4*)dst = d + b4;
            } else {
                *(f32x4*)dst = *(const f32x4*)dst + d;
            }
        }
    }
}

// ---------------- smn = 3x3 conv(acc[4:68]) + mask_b  (plain f32) ----------------
__global__ void k_smn(const float* __restrict__ accp, const float* __restrict__ mw,
                      const float* __restrict__ mb, float* __restrict__ smn)
{
    int px = blockIdx.x*256 + threadIdx.x;
    int row = px >> 8, col = px & 255;
    float s0 = mb[0], s1 = mb[1];
    for (int ky = 0; ky < 3; ++ky) {
        int r = row + ky - 1;
        if ((unsigned)r > 255u) continue;
        for (int kx = 0; kx < 3; ++kx) {
            int c = col + kx - 1;
            if ((unsigned)c > 255u) continue;
            const float* ab = accp + ((size_t)r*256 + c)*72 + 4;
            const float* w  = mw + ky*3 + kx;
#pragma unroll
            for (int ch = 0; ch < 64; ch += 4) {
                f32x4 v = *(const f32x4*)(ab + ch);
                s0 += v[0]*w[(ch+0)*9] + v[1]*w[(ch+1)*9] + v[2]*w[(ch+2)*9] + v[3]*w[(ch+3)*9];
                s1 += v[0]*w[(64+ch+0)*9] + v[1]*w[(64+ch+1)*9] + v[2]*w[(64+ch+2)*9] + v[3]*w[(64+ch+3)*9];
            }
        }
    }
    smn[px]        = s0;
    smn[NPIX + px] = s1;
}

// ---------------- bilinear 2x upsample of acc (68 ch) → d_out[0..68) ----------------
__global__ void k_upsample(const float* __restrict__ accp, float* __restrict__ outp)
{
    int o = blockIdx.x*256 + threadIdx.x;
    int oy = o >> 9, ox = o & 511;
    int my = oy >> 1, mx = ox >> 1;
    int r0, r1, c0, c1; float wy0, wy1, wx0, wx1;
    if (oy & 1) { r0 = my;            r1 = min(my+1, 255); wy0 = 0.75f; wy1 = 0.25f; }
    else        { r0 = max(my-1, 0);  r1 = my;             wy0 = 0.25f; wy1 = 0.75f; }
    if (ox & 1) { c0 = mx;            c1 = min(mx+1, 255); wx0 = 0.75f; wx1 = 0.25f; }
    else        { c0 = max(mx-1, 0);  c1 = mx;             wx0 = 0.25f; wx1 = 0.75f; }
    const float* p00 = accp + ((size_t)r0*256 + c0)*72;
    const float* p01 = accp + ((size_t)r0*256 + c1)*72;
    const float* p10 = accp + ((size_t)r1*256 + c0)*72;
    const float* p11 = accp + ((size_t)r1*256 + c1)*72;
    float w00 = wy0*wx0, w01 = wy0*wx1, w10 = wy1*wx0, w11 = wy1*wx1;
#pragma unroll
    for (int ch = 0; ch < 68; ch += 4) {
        f32x4 va = *(const f32x4*)(p00 + ch);
        f32x4 vb = *(const f32x4*)(p01 + ch);
        f32x4 vc = *(const f32x4*)(p10 + ch);
        f32x4 vd = *(const f32x4*)(p11 + ch);
        f32x4 v;
#pragma unroll
        for (int r = 0; r < 4; ++r)
            v[r] = w00*va[r] + w01*vb[r] + w10*vc[r] + w11*vd[r];
        outp[(size_t)(ch+0)*262144 + o] = v[0];
        outp[(size_t)(ch+1)*262144 + o] = v[1];
        outp[(size_t)(ch+2)*262144 + o] = v[2];
        outp[(size_t)(ch+3)*262144 + o] = v[3];
    }
}

// ---------------- mask_next = (up(smn0) > up(smn1)) * repeat2(space_mask) ----------------
__global__ void k_mask(const float* __restrict__ smn, const float* __restrict__ sm,
                       float* __restrict__ outp)
{
    int o = blockIdx.x*256 + threadIdx.x;
    int oy = o >> 9, ox = o & 511;
    int my = oy >> 1, mx = ox >> 1;
    int r0, r1, c0, c1; float wy0, wy1, wx0, wx1;
    if (oy & 1) { r0 = my;            r1 = min(my+1, 255); wy0 = 0.75f; wy1 = 0.25f; }
    else        { r0 = max(my-1, 0);  r1 = my;             wy0 = 0.25f; wy1 = 0.75f; }
    if (ox & 1) { c0 = mx;            c1 = min(mx+1, 255); wx0 = 0.75f; wx1 = 0.25f; }
    else        { c0 = max(mx-1, 0);  c1 = mx;             wx0 = 0.25f; wx1 = 0.75f; }
    float w00 = wy0*wx0, w01 = wy0*wx1, w10 = wy1*wx0, w11 = wy1*wx1;
    int i00 = r0*256 + c0, i01 = r0*256 + c1, i10 = r1*256 + c0, i11 = r1*256 + c1;
    float s0 = w00*smn[i00] + w01*smn[i01] + w10*smn[i10] + w11*smn[i11];
    float s1 = w00*smn[NPIX+i00] + w01*smn[NPIX+i01] + w10*smn[NPIX+i10] + w11*smn[NPIX+i11];
    outp[(size_t)68*262144 + o] = (s0 > s1) ? sm[my*256 + mx] : 0.f;
}

// ---------------- launcher ----------------
extern "C" void kernel_launch(void* const* d_in, const int* in_sizes, int n_in,
                              void* d_out, int out_size, void* d_ws, size_t ws_size,
                              hipStream_t stream)
{
    const float* feat0  = (const float*)d_in[0];
    const float* feat1  = (const float*)d_in[1];
    const float* featd  = (const float*)d_in[2];
    const float* flow   = (const float*)d_in[3];
    const float* smask  = (const float*)d_in[4];
    const float* head_w = (const float*)d_in[5];
    const float* head_a = (const float*)d_in[6];
    const float* conv_w = (const float*)d_in[7];
    const float* conv_a = (const float*)d_in[8];
    const float* last_w = (const float*)d_in[9];
    const float* last_b = (const float*)d_in[10];
    const float* mask_w = (const float*)d_in[11];
    const float* mask_b = (const float*)d_in[12];
    float* outp = (float*)d_out;

    char* ws = (char*)d_ws;
    size_t off = 0;
    f16* bufA = (f16*)(ws + off); off += SBUF;
    f16* bufB = (f16*)(ws + off); off += SBUF;
    f16* packc = (f16*)(ws + off); off += (size_t)4*PK_CONV*2;
    f16* packl = (f16*)(ws + off); off += (size_t)4*PKL_BI*2;
    float* accp = (float*)(ws + off); off += (size_t)NPIX*72*4;
    float* smn  = (float*)(ws + off); off += (size_t)2*NPIX*4;

    // zero pad rows (stored rows 0 and 257) of both buffers; then halo columns
    hipMemsetAsync(bufA, 0, RBYTES, stream);
    hipMemsetAsync((char*)bufA + (size_t)257*RBYTES, 0, RBYTES, stream);
    hipMemsetAsync(bufB, 0, RBYTES, stream);
    hipMemsetAsync((char*)bufB + (size_t)257*RBYTES, 0, RBYTES, stream);
    k_zero_halo<<<226, 256, 0, stream>>>(bufA, bufB);

    // 4 layers x 1764 frags x 64 lanes = 451,584 threads (dead slices skipped inside)
    k_pack_conv<<<1764, 256, 0, stream>>>(head_w, conv_w, packc);
    k_pack_last<<<70, 256, 0, stream>>>(last_w, packl);
    k_warp_concat<<<256, 256, 0, stream>>>(feat0, feat1, featd, flow, bufA);

    // head: x0(bufA) -> bufB = outs[0]
    k_conv32<<<512, 256, 0, stream>>>(bufA, bufB, packc, head_a, smask);
    k_acc_last<<<512, 256, 0, stream>>>(bufB, packl, last_b, accp, 0);
    // layer1: bufB -> bufA = outs[1]
    k_conv32<<<512, 256, 0, stream>>>(bufB, bufA, packc + (size_t)1*PK_CONV, conv_a, smask);
    k_acc_last<<<512, 256, 0, stream>>>(bufA, packl, last_b, accp, 1);
    // layer2: bufA -> bufB = outs[2]
    k_conv32<<<512, 256, 0, stream>>>(bufA, bufB, packc + (size_t)2*PK_CONV, conv_a + 196, smask);
    k_acc_last<<<512, 256, 0, stream>>>(bufB, packl, last_b, accp, 2);
    // layer3: bufB -> bufA = outs[3]
    k_conv32<<<512, 256, 0, stream>>>(bufB, bufA, packc + (size_t)3*PK_CONV, conv_a + 392, smask);
    k_acc_last<<<512, 256, 0, stream>>>(bufA, packl, last_b, accp, 3);

    k_smn<<<256, 256, 0, stream>>>(accp, mask_w, mask_b, smn);
    k_upsample<<<1024, 256, 0, stream>>>(accp, outp);
    k_mask<<<1024, 256, 0, stream>>>(smn, smask, outp);
}

// Round 15
// 774.910 us; speedup vs baseline: 1.0767x; 1.0767x over previous
//
#include <hip/hip_runtime.h>

typedef _Float16 f16;
typedef _Float16 f16x8 __attribute__((ext_vector_type(8)));
typedef _Float16 f16x4 __attribute__((ext_vector_type(4)));
typedef float    f32x4 __attribute__((ext_vector_type(4)));
typedef float    f32x16 __attribute__((ext_vector_type(16)));

#define MFMA16(a,b,c) __builtin_amdgcn_mfma_f32_16x16x32_f16(a,b,c,0,0,0)
#define MFMA32(a,b,c) __builtin_amdgcn_mfma_f32_32x32x16_f16(a,b,c,0,0,0)

#define AS1 __attribute__((address_space(1)))
#define AS3 __attribute__((address_space(3)))

#define NPIX 65536
// activation layout (halves): [row 258][cb 7][h 2][k16 2][kh 2][px 258][8]
#define PXS   8
#define KHS   2064      // 258*8
#define K16S  4128
#define HS    8256
#define CBS   16512
#define ROWH  115584    // halves per row
#define RBYTES 231168
#define SBUF  ((size_t)258*RBYTES)   // 59,641,344 B

// conv weight pack (halves): 117 LIVE slices per layer, slice = [sel 2][ob 7][lane 64][8]
// slice order: ky-major, cb, k16 (cb=6 has only k16=0 — ic 208..223 are zero pad), kx
#define PKSUB  7168
#define PK_CONV 903168   // per-layer stride (126 slots; tail unused)
#define NMICRO 117

// last (1x1) pack strides (halves)
#define PKL_CB  5120
#define PKL_BI  35840

#define ASTG 14336

// ---------------- weight packing: 3x3 convs, 32x32 A-fragment order ----------------
__global__ void k_pack_conv(const float* __restrict__ head_w,
                            const float* __restrict__ conv_w,
                            f16* __restrict__ dst)
{
    int t = blockIdx.x*256 + threadIdx.x;
    int lane = t & 63; t >>= 6;
    int ob  = t % 7;  t /= 7;
    int sel = t & 1;  t >>= 1;
    int kx  = t % 3;  t /= 3;
    int k16 = t & 1;  t >>= 1;
    int cb  = t % 7;  t /= 7;
    int ky  = t % 3;  t /= 3;
    int li  = t;
    if (li >= 4) return;
    if (cb == 6 && k16 == 1) return;          // dead slice: ic 208..223 all zero
    const float* W = (li == 0) ? head_w : (conv_w + (size_t)(li-1)*196*196*9);
    int oc  = ob*32 + (lane & 31);
    int ic0 = cb*32 + k16*16 + (lane >> 5)*8;
    int tap = ky*3 + kx;
    f16x8 v;
#pragma unroll
    for (int j = 0; j < 8; ++j) {
        int ic = ic0 + j;
        float x = 0.f;
        if (oc < 196 && ic < 196) x = W[((size_t)oc*196 + ic)*9 + tap];
        f16 h = (f16)x;
        v[j] = (sel == 0) ? h : (f16)(x - (float)h);
    }
    int pos = ky*39 + ((cb < 6) ? (cb*6 + k16*3 + kx) : (36 + kx));
    *(f16x8*)(dst + (size_t)li*PK_CONV + (size_t)pos*PKSUB
              + (size_t)(sel*7 + ob)*512 + (size_t)lane*8) = v;
}

__global__ void k_pack_last(const float* __restrict__ last_w, f16* __restrict__ dst)
{
    int t = blockIdx.x*256 + threadIdx.x;
    if (t >= 4*7*5*2*64) return;
    int lane = t & 63; t >>= 6;
    int sel  = t & 1;  t >>= 1;
    int ob   = t % 5;  t /= 5;
    int cb   = t % 7;  t /= 7;
    int bi   = t;
    int oc = ob*16 + (lane & 15);
    int k0 = cb*32 + (lane >> 4)*8;
    f16x8 v;
#pragma unroll
    for (int j = 0; j < 8; ++j) {
        int k = k0 + j;
        float x = 0.f;
        if (oc < 68 && k < 196) x = last_w[(size_t)oc*784 + bi*196 + k];
        f16 h = (f16)x;
        v[j] = (sel == 0) ? h : (f16)(x - (float)h);
    }
    *(f16x8*)(dst + (((size_t)((bi*7+cb)*5 + ob)*2 + sel)*64 + lane)*8) = v;
}

// ---------------- zero the halo px-slots (0 and 257) of every row/slice ----------------
__global__ void k_zero_halo(f16* __restrict__ bufA, f16* __restrict__ bufB)
{
    int c = blockIdx.x*256 + threadIdx.x;
    int end = c & 1; c >>= 1;
    int kh  = c & 1; c >>= 1;
    int k16 = c & 1; c >>= 1;
    int h   = c & 1; c >>= 1;
    int cb  = c % 7; c /= 7;
    int row = c % 258; c /= 258;
    if (c >= 2) return;
    f16* base = (c == 0) ? bufA : bufB;
    f16* p = base + (size_t)row*ROWH + cb*CBS + h*HS + k16*K16S + kh*KHS + (end ? 257 : 0)*PXS;
    f16x8 z = {(f16)0,(f16)0,(f16)0,(f16)0,(f16)0,(f16)0,(f16)0,(f16)0};
    *(f16x8*)p = z;
}

// ---------------- warp + concat → x0 ----------------
struct Gath { int o00,o01,o10,o11; float w00,w01,w10,w11; };

__device__ inline Gath mk_gath(float pxf, float pyf)
{
    float x0 = floorf(pxf), y0 = floorf(pyf);
    float x1 = x0 + 1.f, y1 = y0 + 1.f;
    float wx1 = pxf - x0, wx0 = 1.f - wx1;
    float wy1 = pyf - y0, wy0 = 1.f - wy1;
    bool vx0 = (x0 >= 0.f) && (x0 <= 255.f);
    bool vx1 = (x1 >= 0.f) && (x1 <= 255.f);
    bool vy0 = (y0 >= 0.f) && (y0 <= 255.f);
    bool vy1 = (y1 >= 0.f) && (y1 <= 255.f);
    int ix0 = min(max((int)x0, 0), 255);
    int ix1 = min(max((int)x1, 0), 255);
    int iy0 = min(max((int)y0, 0), 255);
    int iy1 = min(max((int)y1, 0), 255);
    Gath g;
    g.o00 = iy0*256 + ix0; g.w00 = (vx0 && vy0) ? wx0*wy0 : 0.f;
    g.o01 = iy0*256 + ix1; g.w01 = (vx1 && vy0) ? wx1*wy0 : 0.f;
    g.o10 = iy1*256 + ix0; g.w10 = (vx0 && vy1) ? wx0*wy1 : 0.f;
    g.o11 = iy1*256 + ix1; g.w11 = (vx1 && vy1) ? wx1*wy1 : 0.f;
    return g;
}

__device__ inline void store4n(f16* __restrict__ rowb, int slot, int c0,
                               float a, float b, float c, float d)
{
    f16x4 hi, lo;
    f16 h;
    h = (f16)a; hi[0] = h; lo[0] = (f16)(a - (float)h);
    h = (f16)b; hi[1] = h; lo[1] = (f16)(b - (float)h);
    h = (f16)c; hi[2] = h; lo[2] = (f16)(c - (float)h);
    h = (f16)d; hi[3] = h; lo[3] = (f16)(d - (float)h);
    int cb = c0 >> 5, w32 = c0 & 31;
    f16* p = rowb + cb*CBS + (w32 >> 4)*K16S + ((w32 >> 3) & 1)*KHS
                 + (size_t)slot*PXS + (w32 & 7);
    *(f16x4*)p        = hi;
    *(f16x4*)(p + HS) = lo;
}

__global__ void k_warp_concat(const float* __restrict__ f0, const float* __restrict__ f1,
                              const float* __restrict__ fd, const float* __restrict__ flow,
                              f16* __restrict__ out)
{
    int px = blockIdx.x*256 + threadIdx.x;
    int row = px >> 8, col = px & 255;
    f16* rowb = out + (size_t)(row+1)*ROWH;
    int slot = col + 1;
    Gath g0 = mk_gath((float)col + flow[px],          (float)row + flow[NPIX   + px]);
    Gath g1 = mk_gath((float)col + flow[2*NPIX + px], (float)row + flow[3*NPIX + px]);
#pragma unroll
    for (int c = 0; c < 64; c += 4) {
        float v[4];
#pragma unroll
        for (int r = 0; r < 4; ++r) {
            const float* im = f0 + (size_t)(c+r)*NPIX;
            v[r] = g0.w00*im[g0.o00] + g0.w01*im[g0.o01] + g0.w10*im[g0.o10] + g0.w11*im[g0.o11];
        }
        store4n(rowb, slot, c, v[0], v[1], v[2], v[3]);
    }
#pragma unroll
    for (int c = 0; c < 64; c += 4) {
        float v[4];
#pragma unroll
        for (int r = 0; r < 4; ++r) {
            const float* im = f1 + (size_t)(c+r)*NPIX;
            v[r] = g1.w00*im[g1.o00] + g1.w01*im[g1.o01] + g1.w10*im[g1.o10] + g1.w11*im[g1.o11];
        }
        store4n(rowb, slot, 64 + c, v[0], v[1], v[2], v[3]);
    }
#pragma unroll
    for (int c = 0; c < 64; c += 4) {
        store4n(rowb, slot, 128 + c, fd[(size_t)(c+0)*NPIX + px], fd[(size_t)(c+1)*NPIX + px],
                                     fd[(size_t)(c+2)*NPIX + px], fd[(size_t)(c+3)*NPIX + px]);
    }
    store4n(rowb, slot, 192, flow[px], flow[NPIX+px], flow[2*NPIX+px], flow[3*NPIX+px]);
#pragma unroll
    for (int c = 196; c < 224; c += 4) store4n(rowb, slot, c, 0.f, 0.f, 0.f, 0.f);
}

// ---------------- 3x3 conv: R6 structure + 117-micro dead-slice trim ---------------
// 512 blocks x 256 thr (4 waves). Wave = ALL 7 ob32 x one 32-px tile.
// Per micro: stage next A slice (14KB, global_load_lds, linear both sides) + next B
// (2 reg loads, hi/lo); 14 ds_read_b128 + 21 MFMA; one __syncthreads.
__global__ __launch_bounds__(256, 2)
void k_conv32(const f16* __restrict__ in, f16* __restrict__ out,
              const f16* __restrict__ pack, const float* __restrict__ alpha,
              const float* __restrict__ mask)
{
    __shared__ __align__(16) char As[2][ASTG];

    int bid = blockIdx.x;
    int wg  = (bid & 7)*64 + (bid >> 3);      // bijective XCD swizzle (512 % 8 == 0)
    int row  = wg >> 1;
    int half = wg & 1;
    int tid  = threadIdx.x;
    int lane = tid & 63;
    int w    = tid >> 6;
    int pxt  = half*4 + w;
    int l31 = lane & 31, lk = lane >> 5;

    f32x16 acc[7];
#pragma unroll
    for (int o = 0; o < 7; ++o)
#pragma unroll
        for (int e = 0; e < 16; ++e) acc[o][e] = 0.f;

    // stage A slice (896 x 16B chunks), linear both sides
    auto stage = [&](int b, const f16* src) {
        __builtin_amdgcn_global_load_lds(
            (const AS1 void*)(src + (size_t)tid*8),
            (AS3 void*)(&As[b][0] + tid*16), 16, 0, 0);
        __builtin_amdgcn_global_load_lds(
            (const AS1 void*)(src + (size_t)(tid+256)*8),
            (AS3 void*)(&As[b][0] + (tid+256)*16), 16, 0, 0);
        __builtin_amdgcn_global_load_lds(
            (const AS1 void*)(src + (size_t)(tid+512)*8),
            (AS3 void*)(&As[b][0] + (tid+512)*16), 16, 0, 0);
        if (tid < 128)
            __builtin_amdgcn_global_load_lds(
                (const AS1 void*)(src + (size_t)(tid+768)*8),
                (AS3 void*)(&As[b][0] + (tid+768)*16), 16, 0, 0);
    };

    auto lB = [&](const f16* bp, f16x8& H, f16x8& L) {
        H = *(const f16x8*)bp;
        L = *(const f16x8*)(bp + HS);
    };

    // B base: stored slot = pxt*32 + l31 + kx (halo handles the kx-1 shift)
    const f16* bcol = in + (size_t)lk*KHS + (size_t)(pxt*32 + l31)*PXS;

    f16x8 Bh0, Bl0, Bh1, Bl1;
    stage(0, pack);
    lB(bcol + (size_t)row*ROWH, Bh0, Bl0);
    __syncthreads();

    int bsel = 0, q = 0;
    for (int ky = 0; ky < 3; ++ky) {
        const f16* brow = bcol + (size_t)(row + ky)*ROWH;
        for (int cb = 0; cb < 7; ++cb) {
            const f16* bcb = brow + cb*CBS;
            const f16* bnext = (cb < 6) ? (bcb + CBS) : (brow + ROWH);
            int nk16 = (cb == 6) ? 1 : 2;
            for (int k16 = 0; k16 < 2; ++k16) {
                if (k16 >= nk16) break;
#pragma unroll
                for (int kx = 0; kx < 3; ++kx) {
                    bool last = (q == NMICRO - 1);
                    if (!last) {
                        stage(bsel ^ 1, pack + (size_t)(q+1)*PKSUB);
                        const f16* nb;
                        if (kx < 2)                  nb = bcb + k16*K16S + (kx+1)*PXS;
                        else if (k16 == 0 && cb < 6) nb = bcb + K16S;
                        else                         nb = bnext;
                        lB(nb, Bh1, Bl1);
                    }
                    const char* ab = &As[bsel][0];
                    __builtin_amdgcn_s_setprio(1);
#pragma unroll
                    for (int o = 0; o < 7; ++o) {
                        f16x8 Ah = *(const f16x8*)(ab + o*1024 + lane*16);
                        f16x8 Al = *(const f16x8*)(ab + (7+o)*1024 + lane*16);
                        acc[o] = MFMA32(Ah, Bh0, acc[o]);
                        acc[o] = MFMA32(Al, Bh0, acc[o]);
                        acc[o] = MFMA32(Ah, Bl0, acc[o]);
                    }
                    __builtin_amdgcn_s_setprio(0);
                    __syncthreads();
                    bsel ^= 1; ++q;
                    Bh0 = Bh1; Bl0 = Bl1;
                }
            }
        }
    }

    // epilogue: prelu * mask, split-f16 store into the channel-major layout
    float mv = mask[row*256 + pxt*32 + l31];
    f16* orow = out + (size_t)(row+1)*ROWH + (size_t)(pxt*32 + l31 + 1)*PXS + lk*4;
#pragma unroll
    for (int o = 0; o < 7; ++o) {
#pragma unroll
        for (int qg = 0; qg < 4; ++qg) {
            int oc0 = o*32 + 8*qg + 4*lk;
            f32x4 a4 = *(const f32x4*)(alpha + min(oc0, 192));
            f16x4 hi, lo;
#pragma unroll
            for (int e = 0; e < 4; ++e) {
                float v = acc[o][qg*4 + e];
                v = (v >= 0.f ? v : a4[e]*v) * mv;
                f16 h = (f16)v;
                hi[e] = h;
                lo[e] = (f16)(v - (float)h);
            }
            f16* p = orow + o*CBS + (qg >> 1)*K16S + (qg & 1)*KHS;
            *(f16x4*)p        = hi;
            *(f16x4*)(p + HS) = lo;
        }
    }
}

// ---------------- incremental 1x1 last-conv: acc[px][72] (+= / init with bias) ----------------
__global__ __launch_bounds__(256, 4)
void k_acc_last(const f16* __restrict__ in, const f16* __restrict__ pack,
                const float* __restrict__ bias, float* __restrict__ accp, int bi)
{
    int lane = threadIdx.x & 63;
    int wid  = (blockIdx.x << 2) | (threadIdx.x >> 6);
    int row  = wid >> 3;
    int col0 = (wid & 7) << 5;
    int l15 = lane & 15, lk = lane >> 4;

    f32x4 acc[5][2];
#pragma unroll
    for (int i = 0; i < 5; ++i)
#pragma unroll
        for (int j = 0; j < 2; ++j)
            acc[i][j] = (f32x4){0.f, 0.f, 0.f, 0.f};

    const f16* bb = in + (size_t)(row+1)*ROWH + (size_t)(col0 + l15 + 1)*PXS
                  + (lk >> 1)*K16S + (lk & 1)*KHS;
    const f16* ap = pack + (size_t)bi*PKL_BI + (size_t)lane*8;
    for (int cb = 0; cb < 7; ++cb) {
        f16x8 bh[2], bl[2];
#pragma unroll
        for (int pb = 0; pb < 2; ++pb) {
            const f16* p = bb + cb*CBS + pb*16*PXS;
            bh[pb] = *(const f16x8*)p;
            bl[pb] = *(const f16x8*)(p + HS);
        }
        const f16* a = ap + cb*PKL_CB;
#pragma unroll
        for (int ob = 0; ob < 5; ++ob) {
            f16x8 ah = *(const f16x8*)(a + ob*1024);
            f16x8 al = *(const f16x8*)(a + ob*1024 + 512);
#pragma unroll
            for (int pb = 0; pb < 2; ++pb) {
                acc[ob][pb] = MFMA16(ah, bh[pb], acc[ob][pb]);
                acc[ob][pb] = MFMA16(ah, bl[pb], acc[ob][pb]);
                acc[ob][pb] = MFMA16(al, bh[pb], acc[ob][pb]);
            }
        }
    }
#pragma unroll
    for (int ob = 0; ob < 5; ++ob) {
        int oc0 = ob*16 + lk*4;
        if (oc0 >= 72) continue;           // accp stride is 72 floats
#pragma unroll
        for (int pb = 0; pb < 2; ++pb) {
            int px = row*256 + col0 + pb*16 + l15;
            float* dst = accp + (size_t)px*72 + oc0;
            f32x4 d = acc[ob][pb];
            if (bi == 0) {
                f32x4 b4;
#pragma unroll
                for (int r = 0; r < 4; ++r) b4[r] = bias[min(oc0 + r, 67)];
                *(f32x4*)dst = d + b4;
            } else {
                *(f32x4*)dst = *(const f32x4*)dst + d;
            }
        }
    }
}

// ---------------- smn = 3x3 conv(acc[4:68]) + mask_b  (plain f32) ----------------
__global__ void k_smn(const float* __restrict__ accp, const float* __restrict__ mw,
                      const float* __restrict__ mb, float* __restrict__ smn)
{
    int px = blockIdx.x*256 + threadIdx.x;
    int row = px >> 8, col = px & 255;
    float s0 = mb[0], s1 = mb[1];
    for (int ky = 0; ky < 3; ++ky) {
        int r = row + ky - 1;
        if ((unsigned)r > 255u) continue;
        for (int kx = 0; kx < 3; ++kx) {
            int c = col + kx - 1;
            if ((unsigned)c > 255u) continue;
            const float* ab = accp + ((size_t)r*256 + c)*72 + 4;
            const float* w  = mw + ky*3 + kx;
#pragma unroll
            for (int ch = 0; ch < 64; ch += 4) {
                f32x4 v = *(const f32x4*)(ab + ch);
                s0 += v[0]*w[(ch+0)*9] + v[1]*w[(ch+1)*9] + v[2]*w[(ch+2)*9] + v[3]*w[(ch+3)*9];
                s1 += v[0]*w[(64+ch+0)*9] + v[1]*w[(64+ch+1)*9] + v[2]*w[(64+ch+2)*9] + v[3]*w[(64+ch+3)*9];
            }
        }
    }
    smn[px]        = s0;
    smn[NPIX + px] = s1;
}

// ---------------- fused bilinear 2x upsample (68 ch) + mask_next → d_out -----------
__global__ void k_up(const float* __restrict__ accp, const float* __restrict__ smn,
                     const float* __restrict__ sm, float* __restrict__ outp)
{
    int o = blockIdx.x*256 + threadIdx.x;
    int oy = o >> 9, ox = o & 511;
    int my = oy >> 1, mx = ox >> 1;
    int r0, r1, c0, c1; float wy0, wy1, wx0, wx1;
    if (oy & 1) { r0 = my;            r1 = min(my+1, 255); wy0 = 0.75f; wy1 = 0.25f; }
    else        { r0 = max(my-1, 0);  r1 = my;             wy0 = 0.25f; wy1 = 0.75f; }
    if (ox & 1) { c0 = mx;            c1 = min(mx+1, 255); wx0 = 0.75f; wx1 = 0.25f; }
    else        { c0 = max(mx-1, 0);  c1 = mx;             wx0 = 0.25f; wx1 = 0.75f; }
    float w00 = wy0*wx0, w01 = wy0*wx1, w10 = wy1*wx0, w11 = wy1*wx1;
    int i00 = r0*256 + c0, i01 = r0*256 + c1, i10 = r1*256 + c0, i11 = r1*256 + c1;

    const float* p00 = accp + (size_t)i00*72;
    const float* p01 = accp + (size_t)i01*72;
    const float* p10 = accp + (size_t)i10*72;
    const float* p11 = accp + (size_t)i11*72;
#pragma unroll
    for (int ch = 0; ch < 68; ch += 4) {
        f32x4 va = *(const f32x4*)(p00 + ch);
        f32x4 vb = *(const f32x4*)(p01 + ch);
        f32x4 vc = *(const f32x4*)(p10 + ch);
        f32x4 vd = *(const f32x4*)(p11 + ch);
        f32x4 v;
#pragma unroll
        for (int r = 0; r < 4; ++r)
            v[r] = w00*va[r] + w01*vb[r] + w10*vc[r] + w11*vd[r];
        outp[(size_t)(ch+0)*262144 + o] = v[0];
        outp[(size_t)(ch+1)*262144 + o] = v[1];
        outp[(size_t)(ch+2)*262144 + o] = v[2];
        outp[(size_t)(ch+3)*262144 + o] = v[3];
    }
    float s0 = w00*smn[i00] + w01*smn[i01] + w10*smn[i10] + w11*smn[i11];
    float s1 = w00*smn[NPIX+i00] + w01*smn[NPIX+i01] + w10*smn[NPIX+i10] + w11*smn[NPIX+i11];
    outp[(size_t)68*262144 + o] = (s0 > s1) ? sm[my*256 + mx] : 0.f;
}

// ---------------- launcher ----------------
extern "C" void kernel_launch(void* const* d_in, const int* in_sizes, int n_in,
                              void* d_out, int out_size, void* d_ws, size_t ws_size,
                              hipStream_t stream)
{
    const float* feat0  = (const float*)d_in[0];
    const float* feat1  = (const float*)d_in[1];
    const float* featd  = (const float*)d_in[2];
    const float* flow   = (const float*)d_in[3];
    const float* smask  = (const float*)d_in[4];
    const float* head_w = (const float*)d_in[5];
    const float* head_a = (const float*)d_in[6];
    const float* conv_w = (const float*)d_in[7];
    const float* conv_a = (const float*)d_in[8];
    const float* last_w = (const float*)d_in[9];
    const float* last_b = (const float*)d_in[10];
    const float* mask_w = (const float*)d_in[11];
    const float* mask_b = (const float*)d_in[12];
    float* outp = (float*)d_out;

    char* ws = (char*)d_ws;
    size_t off = 0;
    f16* bufA = (f16*)(ws + off); off += SBUF;
    f16* bufB = (f16*)(ws + off); off += SBUF;
    f16* packc = (f16*)(ws + off); off += (size_t)4*PK_CONV*2;
    f16* packl = (f16*)(ws + off); off += (size_t)4*PKL_BI*2;
    float* accp = (float*)(ws + off); off += (size_t)NPIX*72*4;
    float* smn  = (float*)(ws + off); off += (size_t)2*NPIX*4;

    // zero pad rows (stored rows 0 and 257) of both buffers; then halo columns
    hipMemsetAsync(bufA, 0, RBYTES, stream);
    hipMemsetAsync((char*)bufA + (size_t)257*RBYTES, 0, RBYTES, stream);
    hipMemsetAsync(bufB, 0, RBYTES, stream);
    hipMemsetAsync((char*)bufB + (size_t)257*RBYTES, 0, RBYTES, stream);
    k_zero_halo<<<226, 256, 0, stream>>>(bufA, bufB);

    // 4 layers x 1764 frags x 64 lanes = 451,584 threads (dead slices skipped inside)
    k_pack_conv<<<1764, 256, 0, stream>>>(head_w, conv_w, packc);
    k_pack_last<<<70, 256, 0, stream>>>(last_w, packl);
    k_warp_concat<<<256, 256, 0, stream>>>(feat0, feat1, featd, flow, bufA);

    // head: x0(bufA) -> bufB = outs[0]
    k_conv32<<<512, 256, 0, stream>>>(bufA, bufB, packc, head_a, smask);
    k_acc_last<<<512, 256, 0, stream>>>(bufB, packl, last_b, accp, 0);
    // layer1: bufB -> bufA = outs[1]
    k_conv32<<<512, 256, 0, stream>>>(bufB, bufA, packc + (size_t)1*PK_CONV, conv_a, smask);
    k_acc_last<<<512, 256, 0, stream>>>(bufA, packl, last_b, accp, 1);
    // layer2: bufA -> bufB = outs[2]
    k_conv32<<<512, 256, 0, stream>>>(bufA, bufB, packc + (size_t)2*PK_CONV, conv_a + 196, smask);
    k_acc_last<<<512, 256, 0, stream>>>(bufB, packl, last_b, accp, 2);
    // layer3: bufB -> bufA = outs[3]
    k_conv32<<<512, 256, 0, stream>>>(bufB, bufA, packc + (size_t)3*PK_CONV, conv_a + 392, smask);
    k_acc_last<<<512, 256, 0, stream>>>(bufA, packl, last_b, accp, 3);

    k_smn<<<256, 256, 0, stream>>>(accp, mask_w, mask_b, smn);
    k_up<<<1024, 256, 0, stream>>>(accp, smn, smask, outp);
}